// Round 13
// baseline (681.850 us; speedup 1.0000x reference)
//
#include <hip/hip_runtime.h>
#include <math.h>

#define HIDC 128
#define INC 100
#define OUTC 47
#define QCAP 262144

typedef __attribute__((ext_vector_type(8))) short short8_t;   // 8 bf16 (4 VGPRs)
typedef __attribute__((ext_vector_type(4))) float f32x4;      // MFMA accumulator

__device__ inline unsigned short f2bf(float f) {
    unsigned u = __builtin_bit_cast(unsigned, f);
    unsigned r = (u + 0x7FFFu + ((u >> 16) & 1u)) >> 16;      // RNE
    return (unsigned short)r;
}
__device__ inline float bf2f(unsigned short s) {
    unsigned u = ((unsigned)s) << 16;
    return __builtin_bit_cast(float, u);
}

// ---- own e4m3 codec (FTZ below 2^-6, saturate at 448; encoder never emits NaN/denorm) ----
__device__ inline unsigned char f2fp8(float f) {
    unsigned u = __builtin_bit_cast(unsigned, f);
    unsigned s = (u >> 24) & 0x80u;
    unsigned a = u & 0x7FFFFFFFu;
    if (a < 0x3C800000u) return (unsigned char)s;             // |f| < 2^-6 -> 0
    if (a > 0x43E00000u) a = 0x43E00000u;                     // clamp to 448
    unsigned r = a + 0x7FFFFu + ((a >> 20) & 1u);             // RNE at bit 20
    unsigned e = ((r >> 23) & 0xFFu) - 120u;                  // e4m3 bias 7
    unsigned m = (r >> 20) & 7u;
    return (unsigned char)(s | (e << 3) | m);
}
__device__ inline float fp82f(unsigned char v) {
    unsigned e = (v >> 3) & 0xFu;
    unsigned m = v & 7u;
    unsigned s = ((unsigned)v & 0x80u) << 24;
    if (e == 0) return __builtin_bit_cast(float, s);
    unsigned u = s | ((e + 120u) << 23) | (m << 20);
    return __builtin_bit_cast(float, u);
}

// ---------------- CSR build ----------------

__global__ __launch_bounds__(256) void k_deg(const int* __restrict__ dst, int* __restrict__ deg, int ne) {
    int e = blockIdx.x * 256 + threadIdx.x;
    if (e < ne) atomicAdd(&deg[dst[e]], 1);
}

__global__ __launch_bounds__(256) void k_scan1(const int* __restrict__ deg, int* __restrict__ local_s,
                                               int* __restrict__ bsum, int n) {
    __shared__ int s[256];
    int t = threadIdx.x;
    int i = blockIdx.x * 256 + t;
    int v = (i < n) ? deg[i] : 0;
    s[t] = v;
    __syncthreads();
    for (int off = 1; off < 256; off <<= 1) {
        int add = (t >= off) ? s[t - off] : 0;
        __syncthreads();
        s[t] += add;
        __syncthreads();
    }
    if (i < n) local_s[i] = s[t] - v;
    if (t == 255) bsum[blockIdx.x] = s[255];
}

__global__ __launch_bounds__(512) void k_scan2(int* __restrict__ bsum, int nb) {
    __shared__ int s[512];
    int t = threadIdx.x;
    int v = (t < nb) ? bsum[t] : 0;
    s[t] = v;
    __syncthreads();
    for (int off = 1; off < 512; off <<= 1) {
        int add = (t >= off) ? s[t - off] : 0;
        __syncthreads();
        s[t] += add;
        __syncthreads();
    }
    if (t < nb) bsum[t] = s[t] - v;
}

__global__ __launch_bounds__(256) void k_scan3(const int* __restrict__ local_s, const int* __restrict__ bsum,
                                               int* __restrict__ offs, int n, int ne) {
    int i = blockIdx.x * 256 + threadIdx.x;
    if (i < n) offs[i] = local_s[i] + bsum[blockIdx.x];
    if (i == 0) offs[n] = ne;
}

__global__ __launch_bounds__(256) void k_invdeg(const int* __restrict__ deg, float* __restrict__ invdeg, int n) {
    int i = blockIdx.x * 256 + threadIdx.x;
    if (i < n) invdeg[i] = 1.0f / (float)max(deg[i], 1);
}

// ---- Two-pass binned fill (r11/r12 verified) ----

__global__ __launch_bounds__(256) void k_bin2(const int* __restrict__ src, const int* __restrict__ dst,
                                              long long* __restrict__ queue, int* __restrict__ qcur,
                                              int ne, int psize) {
    __shared__ int cnt[8];
    __shared__ int cnt2[8];
    __shared__ int gbase[8];
    int t = threadIdx.x;
    if (t < 8) { cnt[t] = 0; cnt2[t] = 0; }
    __syncthreads();
    int e0 = blockIdx.x * 2048;
    int pl[8], dl[8], sl[8];
#pragma unroll
    for (int i = 0; i < 8; i++) {
        int e = e0 + t + i * 256;
        bool ok = e < ne;
        int d = ok ? dst[e] : 0;
        int s = ok ? src[e] : 0;
        int p = d / psize;
        pl[i] = ok ? p : -1;
        dl[i] = d; sl[i] = s;
        if (ok) atomicAdd(&cnt[p], 1);
    }
    __syncthreads();
    if (t < 8) gbase[t] = atomicAdd(&qcur[t], cnt[t]);
    __syncthreads();
#pragma unroll
    for (int i = 0; i < 8; i++) {
        int p = pl[i];
        if (p >= 0) {
            int r = atomicAdd(&cnt2[p], 1);
            int idx = gbase[p] + r;
            if (idx < QCAP)
                queue[(size_t)p * QCAP + idx] =
                    (long long)(((unsigned long long)(unsigned)dl[i] << 32) | (unsigned)sl[i]);
        }
    }
}

// 2048 blocks (r12: 9% occupancy was the limiter); &7 -> XCD mapping kept.

__global__ __launch_bounds__(256) void k_scatter(const long long* __restrict__ queue,
                                                 const int* __restrict__ qcur,
                                                 const int* __restrict__ offs, int* __restrict__ curs,
                                                 int* __restrict__ csr) {
    int p = blockIdx.x & 7;
    int sub = blockIdx.x >> 3;
    int nsub = gridDim.x >> 3;
    int cnt = min(qcur[p], QCAP);
    const long long* q = queue + (size_t)p * QCAP;
    for (int i = sub * 256 + threadIdx.x; i < cnt; i += nsub * 256) {
        unsigned long long pk = (unsigned long long)q[i];
        int d = (int)(pk >> 32);
        int s = (int)(pk & 0xffffffffu);
        int pos = atomicAdd(&curs[d], 1);
        csr[offs[d] + pos] = s;
    }
}

// ---------------- Weight prep ----------------

__global__ __launch_bounds__(256) void k_prepw(const float* __restrict__ wl_h, const float* __restrict__ wr_h,
                                               unsigned short* __restrict__ wt) {
    int idx = blockIdx.x * 256 + threadIdx.x;
    if (idx >= 6 * 16384) return;
    int m = idx >> 14, rem = idx & 16383;
    int l = m >> 1, s = m & 1;
    const float* srcm = (s == 0 ? wl_h : wr_h) + (size_t)l * 16384;
    wt[idx] = f2bf(srcm[(rem & 127) * 128 + (rem >> 7)]);
}

__global__ __launch_bounds__(256) void k_prepw_out(const float* __restrict__ wl_out,
                                                   const float* __restrict__ wr_out,
                                                   unsigned short* __restrict__ wt2) {
    int idx = blockIdx.x * 256 + threadIdx.x;
    if (idx >= 2 * 48 * 128) return;
    int s = idx / (48 * 128), rem = idx % (48 * 128);
    int nc = rem >> 7, k = rem & 127;
    const float* srcm = (s == 0) ? wl_out : wr_out;
    wt2[idx] = (nc < OUTC) ? f2bf(srcm[k * OUTC + nc]) : 0;
}

__global__ __launch_bounds__(256) void k_prepw_in(const float* __restrict__ w,
                                                  unsigned short* __restrict__ wtin) {
    int idx = blockIdx.x * 256 + threadIdx.x;
    if (idx >= 128 * 128) return;
    int nc = idx >> 7, k = idx & 127;
    wtin[idx] = (k < INC) ? f2bf(w[k * HIDC + nc]) : 0;
}

// ---------------- Aggregation: gather from fp8 shadow table (128B/row) ----------------

__global__ __launch_bounds__(256) void k_agg(const unsigned char* __restrict__ h8, const int* __restrict__ csr,
                                             const int* __restrict__ offs, const float* __restrict__ invdeg,
                                             unsigned short* __restrict__ agg, int n) {
    int wv = threadIdx.x >> 6, lane = threadIdx.x & 63;
    int v = blockIdx.x * 4 + wv;
    if (v >= n) return;
    int q = lane >> 4, c = lane & 15;   // q: edge slot, c: 8B chunk (8 fp8)
    int e0 = offs[v], e1 = offs[v + 1];
    float acc[8] = {0, 0, 0, 0, 0, 0, 0, 0};
    for (int e = e0 + q; e < e1; e += 8) {
        int s0 = csr[e];
        bool has2 = (e + 4) < e1;
        int s1 = has2 ? csr[e + 4] : s0;
        unsigned long long q0 = *reinterpret_cast<const unsigned long long*>(h8 + (size_t)s0 * HIDC + c * 8);
        unsigned long long q1 = *reinterpret_cast<const unsigned long long*>(h8 + (size_t)s1 * HIDC + c * 8);
#pragma unroll
        for (int i = 0; i < 8; i++) {
            acc[i] += fp82f((unsigned char)(q0 >> (8 * i)));
            if (has2) acc[i] += fp82f((unsigned char)(q1 >> (8 * i)));
        }
    }
#pragma unroll
    for (int i = 0; i < 8; i++) {
        acc[i] += __shfl_xor(acc[i], 16);
        acc[i] += __shfl_xor(acc[i], 32);
    }
    if (q == 0) {
        float s = invdeg[v];
        unsigned short o[8];
#pragma unroll
        for (int i = 0; i < 8; i++) o[i] = f2bf(acc[i] * s);
        *reinterpret_cast<short8_t*>(agg + (size_t)v * HIDC + c * 8) = *reinterpret_cast<const short8_t*>(o);
    }
}

// ---------------- Input projection via MFMA (writes h bf16 + h8 fp8) ----------------

__global__ __launch_bounds__(256) void k_inproj_mfma(const float* __restrict__ x,
                                                     const unsigned short* __restrict__ wtin, // [128][128]
                                                     const float* __restrict__ b,
                                                     unsigned short* __restrict__ inp,
                                                     unsigned short* __restrict__ h,
                                                     unsigned char* __restrict__ h8, int n) {
    __shared__ unsigned short sX[32 * 128];
    int t = threadIdx.x;
    int w = t >> 6, lane = t & 63;
    int cc = lane & 15, kg = lane >> 4;
    int row0 = blockIdx.x * 32;

    short8_t bfrag[2][4];
#pragma unroll
    for (int ci = 0; ci < 2; ci++) {
        int ncol = 32 * w + ci * 16 + cc;
        const unsigned short* bp = wtin + ncol * 128 + kg * 8;
#pragma unroll
        for (int ks = 0; ks < 4; ks++)
            bfrag[ci][ks] = *reinterpret_cast<const short8_t*>(bp + ks * 32);
    }

    {
        int r = t >> 3, seg = t & 7;
        int row = row0 + r;
        float v[16];
#pragma unroll
        for (int i = 0; i < 16; i++) v[i] = 0.f;
        if (row < n) {
            const float* xr = x + (size_t)row * INC;
            if (seg < 6) {
#pragma unroll
                for (int j = 0; j < 4; j++) {
                    float4 f = *reinterpret_cast<const float4*>(xr + seg * 16 + j * 4);
                    v[j * 4 + 0] = f.x; v[j * 4 + 1] = f.y; v[j * 4 + 2] = f.z; v[j * 4 + 3] = f.w;
                }
            } else if (seg == 6) {
                float4 f = *reinterpret_cast<const float4*>(xr + 96);
                v[0] = f.x; v[1] = f.y; v[2] = f.z; v[3] = f.w;
            }
        }
        unsigned short o[16];
#pragma unroll
        for (int i = 0; i < 16; i++) o[i] = f2bf(v[i]);
#pragma unroll
        for (int half = 0; half < 2; half++) {
            int g = seg * 2 + half;
            unsigned byte = r * 256 + (((unsigned)g * 16) ^ (((unsigned)r & 7) << 4));
            *reinterpret_cast<short8_t*>(reinterpret_cast<char*>(sX) + byte) =
                *reinterpret_cast<const short8_t*>(&o[half * 8]);
        }
    }
    __syncthreads();

    f32x4 acc[2][2];
#pragma unroll
    for (int rt = 0; rt < 2; rt++)
#pragma unroll
        for (int ci = 0; ci < 2; ci++) acc[rt][ci] = (f32x4){0.f, 0.f, 0.f, 0.f};

#pragma unroll
    for (int ks = 0; ks < 4; ks++) {
        short8_t af[2];
#pragma unroll
        for (int rt = 0; rt < 2; rt++) {
            int r = rt * 16 + cc;
            unsigned byte = r * 256 + (((unsigned)(ks * 64 + kg * 16)) ^ (((unsigned)r & 7) << 4));
            af[rt] = *reinterpret_cast<const short8_t*>(reinterpret_cast<const char*>(sX) + byte);
        }
#pragma unroll
        for (int rt = 0; rt < 2; rt++)
#pragma unroll
            for (int ci = 0; ci < 2; ci++)
                acc[rt][ci] = __builtin_amdgcn_mfma_f32_16x16x32_bf16(af[rt], bfrag[ci][ks],
                                                                      acc[rt][ci], 0, 0, 0);
    }

#pragma unroll
    for (int rt = 0; rt < 2; rt++)
#pragma unroll
        for (int ci = 0; ci < 2; ci++) {
            int col = 32 * w + ci * 16 + cc;
            float bv = b[col];
#pragma unroll
            for (int reg = 0; reg < 4; reg++) {
                int row = row0 + rt * 16 + kg * 4 + reg;
                if (row < n) {
                    float v = acc[rt][ci][reg] + bv;
                    float rl = fmaxf(v, 0.f);
                    inp[(size_t)row * HIDC + col] = f2bf(v);
                    h[(size_t)row * HIDC + col] = f2bf(rl);
                    h8[(size_t)row * HIDC + col] = f2fp8(rl);
                }
            }
        }
}

// ---------------- Hidden SAGE layer via MFMA (writes h bf16 + h8 fp8) ----------------

__global__ __launch_bounds__(256) void k_sage_mfma(const unsigned short* __restrict__ agg,
                                                   unsigned short* __restrict__ h,
                                                   unsigned char* __restrict__ h8,
                                                   const unsigned short* __restrict__ inp,
                                                   const unsigned short* __restrict__ wt,  // [2][128][128]
                                                   const float* __restrict__ bl, int n) {
    __shared__ unsigned short sA[2][32 * 128];
    int t = threadIdx.x;
    int w = t >> 6, lane = t & 63;
    int cc = lane & 15, kg = lane >> 4;
    int row0 = blockIdx.x * 32;

    short8_t bfrag[2][2][4];
#pragma unroll
    for (int s = 0; s < 2; s++)
#pragma unroll
        for (int ci = 0; ci < 2; ci++) {
            int ncol = 32 * w + ci * 16 + cc;
            const unsigned short* bp = wt + s * 16384 + ncol * 128 + kg * 8;
#pragma unroll
            for (int ks = 0; ks < 4; ks++)
                bfrag[s][ci][ks] = *reinterpret_cast<const short8_t*>(bp + ks * 32);
        }

    for (int c = t; c < 512; c += 256) {
        int r = c >> 4, g = c & 15;
        int row = row0 + r;
        unsigned byte = r * 256 + (((unsigned)g * 16) ^ (((unsigned)r & 7) << 4));
        short8_t va = {0, 0, 0, 0, 0, 0, 0, 0}, vh = va;
        if (row < n) {
            va = *reinterpret_cast<const short8_t*>(agg + (size_t)row * HIDC + g * 8);
            vh = *reinterpret_cast<const short8_t*>(h + (size_t)row * HIDC + g * 8);
        }
        *reinterpret_cast<short8_t*>(reinterpret_cast<char*>(&sA[0][0]) + byte) = va;
        *reinterpret_cast<short8_t*>(reinterpret_cast<char*>(&sA[1][0]) + byte) = vh;
    }
    __syncthreads();

    f32x4 acc[2][2];
#pragma unroll
    for (int rt = 0; rt < 2; rt++)
#pragma unroll
        for (int ci = 0; ci < 2; ci++) acc[rt][ci] = (f32x4){0.f, 0.f, 0.f, 0.f};

#pragma unroll
    for (int ks = 0; ks < 4; ks++) {
        short8_t af[2][2];
#pragma unroll
        for (int s = 0; s < 2; s++)
#pragma unroll
            for (int rt = 0; rt < 2; rt++) {
                int r = rt * 16 + cc;
                unsigned byte = r * 256 + (((unsigned)(ks * 64 + kg * 16)) ^ (((unsigned)r & 7) << 4));
                af[s][rt] = *reinterpret_cast<const short8_t*>(reinterpret_cast<const char*>(&sA[s][0]) + byte);
            }
#pragma unroll
        for (int s = 0; s < 2; s++)
#pragma unroll
            for (int rt = 0; rt < 2; rt++)
#pragma unroll
                for (int ci = 0; ci < 2; ci++)
                    acc[rt][ci] = __builtin_amdgcn_mfma_f32_16x16x32_bf16(af[s][rt], bfrag[s][ci][ks],
                                                                          acc[rt][ci], 0, 0, 0);
    }

#pragma unroll
    for (int rt = 0; rt < 2; rt++)
#pragma unroll
        for (int ci = 0; ci < 2; ci++) {
            int col = 32 * w + ci * 16 + cc;
            float bv = bl[col];
#pragma unroll
            for (int reg = 0; reg < 4; reg++) {
                int row = row0 + rt * 16 + kg * 4 + reg;
                if (row < n) {
                    float v = acc[rt][ci][reg] + bv;
                    v = fmaxf(v, 0.f) + 0.2f * bf2f(inp[(size_t)row * HIDC + col]);
                    h[(size_t)row * HIDC + col] = f2bf(v);
                    h8[(size_t)row * HIDC + col] = f2fp8(v);
                }
            }
        }
}

// ---------------- Output layer via MFMA + in-register log_softmax ----------------

__global__ __launch_bounds__(256) void k_out_mfma(const unsigned short* __restrict__ agg,
                                                  const unsigned short* __restrict__ h,
                                                  const unsigned short* __restrict__ wt2,  // [2][48][128]
                                                  const float* __restrict__ bl,
                                                  float* __restrict__ out, int n) {
    __shared__ unsigned short sA[2][64 * 128];
    int t = threadIdx.x;
    int w = t >> 6, lane = t & 63;
    int cc = lane & 15, kg = lane >> 4;
    int row0 = blockIdx.x * 64;

    short8_t bfrag[2][3][4];
#pragma unroll
    for (int s = 0; s < 2; s++)
#pragma unroll
        for (int ci = 0; ci < 3; ci++) {
            const unsigned short* bp = wt2 + s * (48 * 128) + (ci * 16 + cc) * 128 + kg * 8;
#pragma unroll
            for (int ks = 0; ks < 4; ks++)
                bfrag[s][ci][ks] = *reinterpret_cast<const short8_t*>(bp + ks * 32);
        }

    for (int c = t; c < 1024; c += 256) {
        int r = c >> 4, g = c & 15;
        int row = row0 + r;
        unsigned byte = r * 256 + (((unsigned)g * 16) ^ (((unsigned)r & 7) << 4));
        short8_t va = {0, 0, 0, 0, 0, 0, 0, 0}, vh = va;
        if (row < n) {
            va = *reinterpret_cast<const short8_t*>(agg + (size_t)row * HIDC + g * 8);
            vh = *reinterpret_cast<const short8_t*>(h + (size_t)row * HIDC + g * 8);
        }
        *reinterpret_cast<short8_t*>(reinterpret_cast<char*>(&sA[0][0]) + byte) = va;
        *reinterpret_cast<short8_t*>(reinterpret_cast<char*>(&sA[1][0]) + byte) = vh;
    }
    __syncthreads();

    f32x4 acc[3];
#pragma unroll
    for (int ci = 0; ci < 3; ci++) acc[ci] = (f32x4){0.f, 0.f, 0.f, 0.f};

#pragma unroll
    for (int ks = 0; ks < 4; ks++) {
        short8_t af[2];
        int r = w * 16 + cc;
        unsigned byte = r * 256 + (((unsigned)(ks * 64 + kg * 16)) ^ (((unsigned)r & 7) << 4));
#pragma unroll
        for (int s = 0; s < 2; s++)
            af[s] = *reinterpret_cast<const short8_t*>(reinterpret_cast<const char*>(&sA[s][0]) + byte);
#pragma unroll
        for (int s = 0; s < 2; s++)
#pragma unroll
            for (int ci = 0; ci < 3; ci++)
                acc[ci] = __builtin_amdgcn_mfma_f32_16x16x32_bf16(af[s], bfrag[s][ci][ks], acc[ci], 0, 0, 0);
    }

#pragma unroll
    for (int reg = 0; reg < 4; reg++) {
        int row = row0 + w * 16 + kg * 4 + reg;
        float val[3];
        float m = -INFINITY;
#pragma unroll
        for (int ci = 0; ci < 3; ci++) {
            int col = ci * 16 + cc;
            val[ci] = (col < OUTC) ? (acc[ci][reg] + bl[col]) : -INFINITY;
            m = fmaxf(m, val[ci]);
        }
#pragma unroll
        for (int off = 1; off < 16; off <<= 1) m = fmaxf(m, __shfl_xor(m, off));
        float s = 0.f;
#pragma unroll
        for (int ci = 0; ci < 3; ci++) {
            int col = ci * 16 + cc;
            if (col < OUTC) s += __expf(val[ci] - m);
        }
#pragma unroll
        for (int off = 1; off < 16; off <<= 1) s += __shfl_xor(s, off);
        float lse = m + logf(s);
        if (row < n) {
#pragma unroll
            for (int ci = 0; ci < 3; ci++) {
                int col = ci * 16 + cc;
                if (col < OUTC) out[(size_t)row * OUTC + col] = val[ci] - lse;
            }
        }
    }
}

// ---------------- Launch ----------------

extern "C" void kernel_launch(void* const* d_in, const int* in_sizes, int n_in,
                              void* d_out, int out_size, void* d_ws, size_t ws_size,
                              hipStream_t stream) {
    const float* x        = (const float*)d_in[0];
    const int*   ei       = (const int*)d_in[1];
    const float* inproj_w = (const float*)d_in[2];
    const float* inproj_b = (const float*)d_in[3];
    const float* wl_h     = (const float*)d_in[4];
    const float* bl_h     = (const float*)d_in[5];
    const float* wr_h     = (const float*)d_in[6];
    const float* wl_out   = (const float*)d_in[7];
    const float* bl_out   = (const float*)d_in[8];
    const float* wr_out   = (const float*)d_in[9];
    float* out = (float*)d_out;

    int n  = in_sizes[0] / INC;   // 100000
    int ne = in_sizes[1] / 2;     // 1600000
    const int* src = ei;
    const int* dst = ei + ne;

    char* ws = (char*)d_ws;
    size_t off = 0;
    auto alloc = [&](size_t bytes) -> void* {
        void* p = ws + off;
        off = (off + bytes + 255) & ~(size_t)255;
        return p;
    };
    unsigned short* inp    = (unsigned short*)alloc((size_t)n * HIDC * 2);
    unsigned short* h      = (unsigned short*)alloc((size_t)n * HIDC * 2);
    unsigned char*  h8     = (unsigned char*)alloc((size_t)n * HIDC);
    unsigned short* agg    = (unsigned short*)alloc((size_t)n * HIDC * 2);
    unsigned short* wt     = (unsigned short*)alloc((size_t)6 * 16384 * 2);
    unsigned short* wt2    = (unsigned short*)alloc((size_t)2 * 48 * 128 * 2);
    unsigned short* wtin   = (unsigned short*)alloc((size_t)128 * 128 * 2);
    int*   deg    = (int*)alloc((size_t)n * 4);
    float* invdeg = (float*)alloc((size_t)n * 4);
    int*   local_s= (int*)alloc((size_t)n * 4);
    int*   bsum   = (int*)alloc(512 * 4);
    int*   offs   = (int*)alloc((size_t)(n + 1) * 4);
    int*   curs   = (int*)alloc((size_t)n * 4);
    int*   csr    = (int*)alloc((size_t)ne * 4);
    long long* queue = (long long*)alloc((size_t)8 * QCAP * 8);
    int*   qcur   = (int*)alloc(8 * 4);

    hipMemsetAsync(deg, 0, (size_t)n * 4, stream);
    hipMemsetAsync(curs, 0, (size_t)n * 4, stream);
    hipMemsetAsync(qcur, 0, 8 * 4, stream);

    int nbE = (ne + 255) / 256;
    int nbN = (n + 255) / 256;
    k_deg<<<nbE, 256, 0, stream>>>(dst, deg, ne);
    k_scan1<<<nbN, 256, 0, stream>>>(deg, local_s, bsum, n);
    k_scan2<<<1, 512, 0, stream>>>(bsum, nbN);
    k_scan3<<<nbN, 256, 0, stream>>>(local_s, bsum, offs, n, ne);
    k_invdeg<<<nbN, 256, 0, stream>>>(deg, invdeg, n);

    int psize = (n + 7) / 8;
    int nbB = (ne + 2047) / 2048;
    k_bin2<<<nbB, 256, 0, stream>>>(src, dst, queue, qcur, ne, psize);
    k_scatter<<<2048, 256, 0, stream>>>(queue, qcur, offs, curs, csr);

    k_prepw<<<(6 * 16384 + 255) / 256, 256, 0, stream>>>(wl_h, wr_h, wt);
    k_prepw_out<<<(2 * 48 * 128 + 255) / 256, 256, 0, stream>>>(wl_out, wr_out, wt2);
    k_prepw_in<<<(128 * 128 + 255) / 256, 256, 0, stream>>>(inproj_w, wtin);

    int nbA = (n + 3) / 4;
    int nbT = (n + 31) / 32;
    int nbO = (n + 63) / 64;
    k_inproj_mfma<<<nbT, 256, 0, stream>>>(x, wtin, inproj_b, inp, h, h8, n);
    for (int l = 0; l < 3; ++l) {
        k_agg<<<nbA, 256, 0, stream>>>(h8, csr, offs, invdeg, agg, n);
        k_sage_mfma<<<nbT, 256, 0, stream>>>(agg, h, h8, inp, wt + (size_t)l * 2 * 16384,
                                             bl_h + (size_t)l * HIDC, n);
    }
    k_agg<<<nbA, 256, 0, stream>>>(h8, csr, offs, invdeg, agg, n);
    k_out_mfma<<<nbO, 256, 0, stream>>>(agg, h, wt2, bl_out, out, n);
}

// Round 14
// 594.162 us; speedup vs baseline: 1.1476x; 1.1476x over previous
//
#include <hip/hip_runtime.h>
#include <math.h>

#define HIDC 128
#define INC 100
#define OUTC 47
#define QCAP 262144

typedef __attribute__((ext_vector_type(8))) short short8_t;   // 8 bf16 (4 VGPRs)
typedef __attribute__((ext_vector_type(4))) float f32x4;      // MFMA accumulator

__device__ inline unsigned short f2bf(float f) {
    unsigned u = __builtin_bit_cast(unsigned, f);
    unsigned r = (u + 0x7FFFu + ((u >> 16) & 1u)) >> 16;      // RNE
    return (unsigned short)r;
}
__device__ inline float bf2f(unsigned short s) {
    unsigned u = ((unsigned)s) << 16;
    return __builtin_bit_cast(float, u);
}

// ---------------- CSR build ----------------

__global__ __launch_bounds__(256) void k_scan1(const int* __restrict__ deg, int* __restrict__ local_s,
                                               int* __restrict__ bsum, int n) {
    __shared__ int s[256];
    int t = threadIdx.x;
    int i = blockIdx.x * 256 + t;
    int v = (i < n) ? deg[i] : 0;
    s[t] = v;
    __syncthreads();
    for (int off = 1; off < 256; off <<= 1) {
        int add = (t >= off) ? s[t - off] : 0;
        __syncthreads();
        s[t] += add;
        __syncthreads();
    }
    if (i < n) local_s[i] = s[t] - v;
    if (t == 255) bsum[blockIdx.x] = s[255];
}

__global__ __launch_bounds__(512) void k_scan2(int* __restrict__ bsum, int nb) {
    __shared__ int s[512];
    int t = threadIdx.x;
    int v = (t < nb) ? bsum[t] : 0;
    s[t] = v;
    __syncthreads();
    for (int off = 1; off < 512; off <<= 1) {
        int add = (t >= off) ? s[t - off] : 0;
        __syncthreads();
        s[t] += add;
        __syncthreads();
    }
    if (t < nb) bsum[t] = s[t] - v;
}

__global__ __launch_bounds__(256) void k_scan3(const int* __restrict__ local_s, const int* __restrict__ bsum,
                                               int* __restrict__ offs, int n, int ne) {
    int i = blockIdx.x * 256 + threadIdx.x;
    if (i < n) offs[i] = local_s[i] + bsum[blockIdx.x];
    if (i == 0) offs[n] = ne;
}

__global__ __launch_bounds__(256) void k_invdeg(const int* __restrict__ deg, float* __restrict__ invdeg, int n) {
    int i = blockIdx.x * 256 + threadIdx.x;
    if (i < n) invdeg[i] = 1.0f / (float)max(deg[i], 1);
}

// ---- Two-pass binned fill; bin pass ALSO accumulates deg (folds old k_deg away) ----

__global__ __launch_bounds__(256) void k_bin2(const int* __restrict__ src, const int* __restrict__ dst,
                                              long long* __restrict__ queue, int* __restrict__ qcur,
                                              int* __restrict__ deg, int ne, int psize) {
    __shared__ int cnt[8];
    __shared__ int cnt2[8];
    __shared__ int gbase[8];
    int t = threadIdx.x;
    if (t < 8) { cnt[t] = 0; cnt2[t] = 0; }
    __syncthreads();
    int e0 = blockIdx.x * 2048;
    int pl[8], dl[8], sl[8];
#pragma unroll
    for (int i = 0; i < 8; i++) {
        int e = e0 + t + i * 256;
        bool ok = e < ne;
        int d = ok ? dst[e] : 0;
        int s = ok ? src[e] : 0;
        int p = d / psize;
        pl[i] = ok ? p : -1;
        dl[i] = d; sl[i] = s;
        if (ok) {
            atomicAdd(&cnt[p], 1);
            atomicAdd(&deg[d], 1);
        }
    }
    __syncthreads();
    if (t < 8) gbase[t] = atomicAdd(&qcur[t], cnt[t]);
    __syncthreads();
#pragma unroll
    for (int i = 0; i < 8; i++) {
        int p = pl[i];
        if (p >= 0) {
            int r = atomicAdd(&cnt2[p], 1);
            int idx = gbase[p] + r;
            if (idx < QCAP)
                queue[(size_t)p * QCAP + idx] =
                    (long long)(((unsigned long long)(unsigned)dl[i] << 32) | (unsigned)sl[i]);
        }
    }
}

// 2048 blocks (r13: occupancy fix verified); &7 -> XCD mapping (r9 verified).

__global__ __launch_bounds__(256) void k_scatter(const long long* __restrict__ queue,
                                                 const int* __restrict__ qcur,
                                                 const int* __restrict__ offs, int* __restrict__ curs,
                                                 int* __restrict__ csr) {
    int p = blockIdx.x & 7;
    int sub = blockIdx.x >> 3;
    int nsub = gridDim.x >> 3;
    int cnt = min(qcur[p], QCAP);
    const long long* q = queue + (size_t)p * QCAP;
    for (int i = sub * 256 + threadIdx.x; i < cnt; i += nsub * 256) {
        unsigned long long pk = (unsigned long long)q[i];
        int d = (int)(pk >> 32);
        int s = (int)(pk & 0xffffffffu);
        int pos = atomicAdd(&curs[d], 1);
        csr[offs[d] + pos] = s;
    }
}

// ---------------- Weight prep ----------------

__global__ __launch_bounds__(256) void k_prepw(const float* __restrict__ wl_h, const float* __restrict__ wr_h,
                                               unsigned short* __restrict__ wt) {
    int idx = blockIdx.x * 256 + threadIdx.x;
    if (idx >= 6 * 16384) return;
    int m = idx >> 14, rem = idx & 16383;
    int l = m >> 1, s = m & 1;
    const float* srcm = (s == 0 ? wl_h : wr_h) + (size_t)l * 16384;
    wt[idx] = f2bf(srcm[(rem & 127) * 128 + (rem >> 7)]);
}

__global__ __launch_bounds__(256) void k_prepw_out(const float* __restrict__ wl_out,
                                                   const float* __restrict__ wr_out,
                                                   unsigned short* __restrict__ wt2) {
    int idx = blockIdx.x * 256 + threadIdx.x;
    if (idx >= 2 * 48 * 128) return;
    int s = idx / (48 * 128), rem = idx % (48 * 128);
    int nc = rem >> 7, k = rem & 127;
    const float* srcm = (s == 0) ? wl_out : wr_out;
    wt2[idx] = (nc < OUTC) ? f2bf(srcm[k * OUTC + nc]) : 0;
}

__global__ __launch_bounds__(256) void k_prepw_in(const float* __restrict__ w,
                                                  unsigned short* __restrict__ wtin) {
    int idx = blockIdx.x * 256 + threadIdx.x;
    if (idx >= 128 * 128) return;
    int nc = idx >> 7, k = idx & 127;
    wtin[idx] = (k < INC) ? f2bf(w[k * HIDC + nc]) : 0;
}

// ---------------- Aggregation (bf16 gather, csr-prefetch pipeline) ----------------
// r13 lesson: fp8 decode made this VALU-bound (89%). bf16 unpack is 2 ops/elem.
// csr indices for iteration i+1 are loaded before processing i's rows, breaking
// the csr-load -> row-load serial latency chain.

__global__ __launch_bounds__(256) void k_agg(const unsigned short* __restrict__ h, const int* __restrict__ csr,
                                             const int* __restrict__ offs, const float* __restrict__ invdeg,
                                             unsigned short* __restrict__ agg, int n) {
    int wv = threadIdx.x >> 6, lane = threadIdx.x & 63;
    int v = blockIdx.x * 4 + wv;
    if (v >= n) return;
    int q = lane >> 4, c = lane & 15;   // q: edge slot, c: 16B chunk (8 bf16)
    int e0 = offs[v], e1 = offs[v + 1];
    float acc[8] = {0, 0, 0, 0, 0, 0, 0, 0};
    int e = e0 + q;
    int s0c = (e < e1) ? csr[e] : 0;
    int s1c = (e + 4 < e1) ? csr[e + 4] : s0c;
    while (e < e1) {
        int s0 = s0c;
        int s1 = s1c;
        bool has2 = (e + 4) < e1;
        int en = e + 8;
        if (en < e1) {                       // prefetch next iteration's indices
            s0c = csr[en];
            s1c = (en + 4 < e1) ? csr[en + 4] : s0c;
        }
        short8_t t0 = *reinterpret_cast<const short8_t*>(h + (size_t)s0 * HIDC + c * 8);
        short8_t t1 = *reinterpret_cast<const short8_t*>(h + (size_t)s1 * HIDC + c * 8);
#pragma unroll
        for (int i = 0; i < 8; i++) {
            acc[i] += bf2f((unsigned short)t0[i]);
            if (has2) acc[i] += bf2f((unsigned short)t1[i]);
        }
        e = en;
    }
#pragma unroll
    for (int i = 0; i < 8; i++) {
        acc[i] += __shfl_xor(acc[i], 16);
        acc[i] += __shfl_xor(acc[i], 32);
    }
    if (q == 0) {
        float s = invdeg[v];
        unsigned short o[8];
#pragma unroll
        for (int i = 0; i < 8; i++) o[i] = f2bf(acc[i] * s);
        *reinterpret_cast<short8_t*>(agg + (size_t)v * HIDC + c * 8) = *reinterpret_cast<const short8_t*>(o);
    }
}

// ---------------- Input projection via MFMA ----------------

__global__ __launch_bounds__(256) void k_inproj_mfma(const float* __restrict__ x,
                                                     const unsigned short* __restrict__ wtin, // [128][128]
                                                     const float* __restrict__ b,
                                                     unsigned short* __restrict__ inp,
                                                     unsigned short* __restrict__ h, int n) {
    __shared__ unsigned short sX[32 * 128];
    int t = threadIdx.x;
    int w = t >> 6, lane = t & 63;
    int cc = lane & 15, kg = lane >> 4;
    int row0 = blockIdx.x * 32;

    short8_t bfrag[2][4];
#pragma unroll
    for (int ci = 0; ci < 2; ci++) {
        int ncol = 32 * w + ci * 16 + cc;
        const unsigned short* bp = wtin + ncol * 128 + kg * 8;
#pragma unroll
        for (int ks = 0; ks < 4; ks++)
            bfrag[ci][ks] = *reinterpret_cast<const short8_t*>(bp + ks * 32);
    }

    {
        int r = t >> 3, seg = t & 7;
        int row = row0 + r;
        float v[16];
#pragma unroll
        for (int i = 0; i < 16; i++) v[i] = 0.f;
        if (row < n) {
            const float* xr = x + (size_t)row * INC;
            if (seg < 6) {
#pragma unroll
                for (int j = 0; j < 4; j++) {
                    float4 f = *reinterpret_cast<const float4*>(xr + seg * 16 + j * 4);
                    v[j * 4 + 0] = f.x; v[j * 4 + 1] = f.y; v[j * 4 + 2] = f.z; v[j * 4 + 3] = f.w;
                }
            } else if (seg == 6) {
                float4 f = *reinterpret_cast<const float4*>(xr + 96);
                v[0] = f.x; v[1] = f.y; v[2] = f.z; v[3] = f.w;
            }
        }
        unsigned short o[16];
#pragma unroll
        for (int i = 0; i < 16; i++) o[i] = f2bf(v[i]);
#pragma unroll
        for (int half = 0; half < 2; half++) {
            int g = seg * 2 + half;
            unsigned byte = r * 256 + (((unsigned)g * 16) ^ (((unsigned)r & 7) << 4));
            *reinterpret_cast<short8_t*>(reinterpret_cast<char*>(sX) + byte) =
                *reinterpret_cast<const short8_t*>(&o[half * 8]);
        }
    }
    __syncthreads();

    f32x4 acc[2][2];
#pragma unroll
    for (int rt = 0; rt < 2; rt++)
#pragma unroll
        for (int ci = 0; ci < 2; ci++) acc[rt][ci] = (f32x4){0.f, 0.f, 0.f, 0.f};

#pragma unroll
    for (int ks = 0; ks < 4; ks++) {
        short8_t af[2];
#pragma unroll
        for (int rt = 0; rt < 2; rt++) {
            int r = rt * 16 + cc;
            unsigned byte = r * 256 + (((unsigned)(ks * 64 + kg * 16)) ^ (((unsigned)r & 7) << 4));
            af[rt] = *reinterpret_cast<const short8_t*>(reinterpret_cast<const char*>(sX) + byte);
        }
#pragma unroll
        for (int rt = 0; rt < 2; rt++)
#pragma unroll
            for (int ci = 0; ci < 2; ci++)
                acc[rt][ci] = __builtin_amdgcn_mfma_f32_16x16x32_bf16(af[rt], bfrag[ci][ks],
                                                                      acc[rt][ci], 0, 0, 0);
    }

#pragma unroll
    for (int rt = 0; rt < 2; rt++)
#pragma unroll
        for (int ci = 0; ci < 2; ci++) {
            int col = 32 * w + ci * 16 + cc;
            float bv = b[col];
#pragma unroll
            for (int reg = 0; reg < 4; reg++) {
                int row = row0 + rt * 16 + kg * 4 + reg;
                if (row < n) {
                    float v = acc[rt][ci][reg] + bv;
                    inp[(size_t)row * HIDC + col] = f2bf(v);
                    h[(size_t)row * HIDC + col] = f2bf(fmaxf(v, 0.f));
                }
            }
        }
}

// ---------------- Hidden SAGE layer via MFMA (inp bf16) ----------------

__global__ __launch_bounds__(256) void k_sage_mfma(const unsigned short* __restrict__ agg,
                                                   unsigned short* __restrict__ h,
                                                   const unsigned short* __restrict__ inp,
                                                   const unsigned short* __restrict__ wt,  // [2][128][128]
                                                   const float* __restrict__ bl, int n) {
    __shared__ unsigned short sA[2][32 * 128];
    int t = threadIdx.x;
    int w = t >> 6, lane = t & 63;
    int cc = lane & 15, kg = lane >> 4;
    int row0 = blockIdx.x * 32;

    short8_t bfrag[2][2][4];
#pragma unroll
    for (int s = 0; s < 2; s++)
#pragma unroll
        for (int ci = 0; ci < 2; ci++) {
            int ncol = 32 * w + ci * 16 + cc;
            const unsigned short* bp = wt + s * 16384 + ncol * 128 + kg * 8;
#pragma unroll
            for (int ks = 0; ks < 4; ks++)
                bfrag[s][ci][ks] = *reinterpret_cast<const short8_t*>(bp + ks * 32);
        }

    for (int c = t; c < 512; c += 256) {
        int r = c >> 4, g = c & 15;
        int row = row0 + r;
        unsigned byte = r * 256 + (((unsigned)g * 16) ^ (((unsigned)r & 7) << 4));
        short8_t va = {0, 0, 0, 0, 0, 0, 0, 0}, vh = va;
        if (row < n) {
            va = *reinterpret_cast<const short8_t*>(agg + (size_t)row * HIDC + g * 8);
            vh = *reinterpret_cast<const short8_t*>(h + (size_t)row * HIDC + g * 8);
        }
        *reinterpret_cast<short8_t*>(reinterpret_cast<char*>(&sA[0][0]) + byte) = va;
        *reinterpret_cast<short8_t*>(reinterpret_cast<char*>(&sA[1][0]) + byte) = vh;
    }
    __syncthreads();

    f32x4 acc[2][2];
#pragma unroll
    for (int rt = 0; rt < 2; rt++)
#pragma unroll
        for (int ci = 0; ci < 2; ci++) acc[rt][ci] = (f32x4){0.f, 0.f, 0.f, 0.f};

#pragma unroll
    for (int ks = 0; ks < 4; ks++) {
        short8_t af[2][2];
#pragma unroll
        for (int s = 0; s < 2; s++)
#pragma unroll
            for (int rt = 0; rt < 2; rt++) {
                int r = rt * 16 + cc;
                unsigned byte = r * 256 + (((unsigned)(ks * 64 + kg * 16)) ^ (((unsigned)r & 7) << 4));
                af[s][rt] = *reinterpret_cast<const short8_t*>(reinterpret_cast<const char*>(&sA[s][0]) + byte);
            }
#pragma unroll
        for (int s = 0; s < 2; s++)
#pragma unroll
            for (int rt = 0; rt < 2; rt++)
#pragma unroll
                for (int ci = 0; ci < 2; ci++)
                    acc[rt][ci] = __builtin_amdgcn_mfma_f32_16x16x32_bf16(af[s][rt], bfrag[s][ci][ks],
                                                                          acc[rt][ci], 0, 0, 0);
    }

#pragma unroll
    for (int rt = 0; rt < 2; rt++)
#pragma unroll
        for (int ci = 0; ci < 2; ci++) {
            int col = 32 * w + ci * 16 + cc;
            float bv = bl[col];
#pragma unroll
            for (int reg = 0; reg < 4; reg++) {
                int row = row0 + rt * 16 + kg * 4 + reg;
                if (row < n) {
                    float v = acc[rt][ci][reg] + bv;
                    v = fmaxf(v, 0.f) + 0.2f * bf2f(inp[(size_t)row * HIDC + col]);
                    h[(size_t)row * HIDC + col] = f2bf(v);
                }
            }
        }
}

// ---------------- Output layer via MFMA + in-register log_softmax ----------------

__global__ __launch_bounds__(256) void k_out_mfma(const unsigned short* __restrict__ agg,
                                                  const unsigned short* __restrict__ h,
                                                  const unsigned short* __restrict__ wt2,  // [2][48][128]
                                                  const float* __restrict__ bl,
                                                  float* __restrict__ out, int n) {
    __shared__ unsigned short sA[2][64 * 128];
    int t = threadIdx.x;
    int w = t >> 6, lane = t & 63;
    int cc = lane & 15, kg = lane >> 4;
    int row0 = blockIdx.x * 64;

    short8_t bfrag[2][3][4];
#pragma unroll
    for (int s = 0; s < 2; s++)
#pragma unroll
        for (int ci = 0; ci < 3; ci++) {
            const unsigned short* bp = wt2 + s * (48 * 128) + (ci * 16 + cc) * 128 + kg * 8;
#pragma unroll
            for (int ks = 0; ks < 4; ks++)
                bfrag[s][ci][ks] = *reinterpret_cast<const short8_t*>(bp + ks * 32);
        }

    for (int c = t; c < 1024; c += 256) {
        int r = c >> 4, g = c & 15;
        int row = row0 + r;
        unsigned byte = r * 256 + (((unsigned)g * 16) ^ (((unsigned)r & 7) << 4));
        short8_t va = {0, 0, 0, 0, 0, 0, 0, 0}, vh = va;
        if (row < n) {
            va = *reinterpret_cast<const short8_t*>(agg + (size_t)row * HIDC + g * 8);
            vh = *reinterpret_cast<const short8_t*>(h + (size_t)row * HIDC + g * 8);
        }
        *reinterpret_cast<short8_t*>(reinterpret_cast<char*>(&sA[0][0]) + byte) = va;
        *reinterpret_cast<short8_t*>(reinterpret_cast<char*>(&sA[1][0]) + byte) = vh;
    }
    __syncthreads();

    f32x4 acc[3];
#pragma unroll
    for (int ci = 0; ci < 3; ci++) acc[ci] = (f32x4){0.f, 0.f, 0.f, 0.f};

#pragma unroll
    for (int ks = 0; ks < 4; ks++) {
        short8_t af[2];
        int r = w * 16 + cc;
        unsigned byte = r * 256 + (((unsigned)(ks * 64 + kg * 16)) ^ (((unsigned)r & 7) << 4));
#pragma unroll
        for (int s = 0; s < 2; s++)
            af[s] = *reinterpret_cast<const short8_t*>(reinterpret_cast<const char*>(&sA[s][0]) + byte);
#pragma unroll
        for (int s = 0; s < 2; s++)
#pragma unroll
            for (int ci = 0; ci < 3; ci++)
                acc[ci] = __builtin_amdgcn_mfma_f32_16x16x32_bf16(af[s], bfrag[s][ci][ks], acc[ci], 0, 0, 0);
    }

#pragma unroll
    for (int reg = 0; reg < 4; reg++) {
        int row = row0 + w * 16 + kg * 4 + reg;
        float val[3];
        float m = -INFINITY;
#pragma unroll
        for (int ci = 0; ci < 3; ci++) {
            int col = ci * 16 + cc;
            val[ci] = (col < OUTC) ? (acc[ci][reg] + bl[col]) : -INFINITY;
            m = fmaxf(m, val[ci]);
        }
#pragma unroll
        for (int off = 1; off < 16; off <<= 1) m = fmaxf(m, __shfl_xor(m, off));
        float s = 0.f;
#pragma unroll
        for (int ci = 0; ci < 3; ci++) {
            int col = ci * 16 + cc;
            if (col < OUTC) s += __expf(val[ci] - m);
        }
#pragma unroll
        for (int off = 1; off < 16; off <<= 1) s += __shfl_xor(s, off);
        float lse = m + logf(s);
        if (row < n) {
#pragma unroll
            for (int ci = 0; ci < 3; ci++) {
                int col = ci * 16 + cc;
                if (col < OUTC) out[(size_t)row * OUTC + col] = val[ci] - lse;
            }
        }
    }
}

// ---------------- Launch ----------------

extern "C" void kernel_launch(void* const* d_in, const int* in_sizes, int n_in,
                              void* d_out, int out_size, void* d_ws, size_t ws_size,
                              hipStream_t stream) {
    const float* x        = (const float*)d_in[0];
    const int*   ei       = (const int*)d_in[1];
    const float* inproj_w = (const float*)d_in[2];
    const float* inproj_b = (const float*)d_in[3];
    const float* wl_h     = (const float*)d_in[4];
    const float* bl_h     = (const float*)d_in[5];
    const float* wr_h     = (const float*)d_in[6];
    const float* wl_out   = (const float*)d_in[7];
    const float* bl_out   = (const float*)d_in[8];
    const float* wr_out   = (const float*)d_in[9];
    float* out = (float*)d_out;

    int n  = in_sizes[0] / INC;   // 100000
    int ne = in_sizes[1] / 2;     // 1600000
    const int* src = ei;
    const int* dst = ei + ne;

    char* ws = (char*)d_ws;
    size_t off = 0;
    auto alloc = [&](size_t bytes) -> void* {
        void* p = ws + off;
        off = (off + bytes + 255) & ~(size_t)255;
        return p;
    };
    unsigned short* inp    = (unsigned short*)alloc((size_t)n * HIDC * 2);
    unsigned short* h      = (unsigned short*)alloc((size_t)n * HIDC * 2);
    unsigned short* agg    = (unsigned short*)alloc((size_t)n * HIDC * 2);
    unsigned short* wt     = (unsigned short*)alloc((size_t)6 * 16384 * 2);
    unsigned short* wt2    = (unsigned short*)alloc((size_t)2 * 48 * 128 * 2);
    unsigned short* wtin   = (unsigned short*)alloc((size_t)128 * 128 * 2);
    int*   deg    = (int*)alloc((size_t)n * 4);
    float* invdeg = (float*)alloc((size_t)n * 4);
    int*   local_s= (int*)alloc((size_t)n * 4);
    int*   bsum   = (int*)alloc(512 * 4);
    int*   offs   = (int*)alloc((size_t)(n + 1) * 4);
    int*   curs   = (int*)alloc((size_t)n * 4);
    int*   csr    = (int*)alloc((size_t)ne * 4);
    long long* queue = (long long*)alloc((size_t)8 * QCAP * 8);
    int*   qcur   = (int*)alloc(8 * 4);

    hipMemsetAsync(deg, 0, (size_t)n * 4, stream);
    hipMemsetAsync(curs, 0, (size_t)n * 4, stream);
    hipMemsetAsync(qcur, 0, 8 * 4, stream);

    int nbN = (n + 255) / 256;
    int psize = (n + 7) / 8;
    int nbB = (ne + 2047) / 2048;

    // bin pass also builds deg; scans follow it
    k_bin2<<<nbB, 256, 0, stream>>>(src, dst, queue, qcur, deg, ne, psize);
    k_scan1<<<nbN, 256, 0, stream>>>(deg, local_s, bsum, n);
    k_scan2<<<1, 512, 0, stream>>>(bsum, nbN);
    k_scan3<<<nbN, 256, 0, stream>>>(local_s, bsum, offs, n, ne);
    k_invdeg<<<nbN, 256, 0, stream>>>(deg, invdeg, n);
    k_scatter<<<2048, 256, 0, stream>>>(queue, qcur, offs, curs, csr);

    k_prepw<<<(6 * 16384 + 255) / 256, 256, 0, stream>>>(wl_h, wr_h, wt);
    k_prepw_out<<<(2 * 48 * 128 + 255) / 256, 256, 0, stream>>>(wl_out, wr_out, wt2);
    k_prepw_in<<<(128 * 128 + 255) / 256, 256, 0, stream>>>(inproj_w, wtin);

    int nbA = (n + 3) / 4;
    int nbT = (n + 31) / 32;
    int nbO = (n + 63) / 64;
    k_inproj_mfma<<<nbT, 256, 0, stream>>>(x, wtin, inproj_b, inp, h, n);
    for (int l = 0; l < 3; ++l) {
        k_agg<<<nbA, 256, 0, stream>>>(h, csr, offs, invdeg, agg, n);
        k_sage_mfma<<<nbT, 256, 0, stream>>>(agg, h, inp, wt + (size_t)l * 2 * 16384,
                                             bl_h + (size_t)l * HIDC, n);
    }
    k_agg<<<nbA, 256, 0, stream>>>(h, csr, offs, invdeg, agg, n);
    k_out_mfma<<<nbO, 256, 0, stream>>>(agg, h, wt2, bl_out, out, n);
}